// Round 6
// baseline (824.786 us; speedup 1.0000x reference)
//
#include <hip/hip_runtime.h>
#include <hip/hip_bf16.h>
#include <stdint.h>

#define B_SZ 64
#define L_SZ 2048
#define V_SZ 1024
#define H_SZ 256
#define HALF_SZ 128
#define NTOK (B_SZ * L_SZ)   // 131072
#define CH 16384             // token chunk (8 chunks)

typedef unsigned short ushort_t;
typedef __attribute__((ext_vector_type(8))) short bf16x8;
typedef __attribute__((ext_vector_type(4))) float f32x4;

__device__ __forceinline__ ushort_t f2bf(float f) {
    __hip_bfloat16 h = __float2bfloat16(f);
    return *reinterpret_cast<ushort_t*>(&h);
}

// ---------------------------------------------------------------------------
// f32 -> bf16 convert (same layout). n multiple of 1024.
// ---------------------------------------------------------------------------
__global__ __launch_bounds__(256) void cvt_bf16_k(
    const float* __restrict__ src, ushort_t* __restrict__ dst, int n)
{
    int i = (blockIdx.x * 256 + threadIdx.x) * 4;
    if (i >= n) return;
    float4 v = *(const float4*)(src + i);
    uint2 pk;
    pk.x = (uint32_t)f2bf(v.x) | ((uint32_t)f2bf(v.y) << 16);
    pk.y = (uint32_t)f2bf(v.z) | ((uint32_t)f2bf(v.w) << 16);
    *(uint2*)(dst + i) = pk;
}

// ---------------------------------------------------------------------------
// dst[n*K + k] = bf16(src[k*N + n])  — weight transpose + convert (tiny).
// ---------------------------------------------------------------------------
__global__ __launch_bounds__(256) void transpose_cvt_k(
    const float* __restrict__ src, ushort_t* __restrict__ dst, int K, int N)
{
    int idx = blockIdx.x * 256 + threadIdx.x;
    if (idx >= K * N) return;
    int n = idx / K;
    int k = idx - n * K;
    dst[idx] = f2bf(src[(size_t)k * N + n]);
}

// ---------------------------------------------------------------------------
// bf16 MFMA GEMM: C[128 x 128-tile] = A[M][K] @ BT[N][K]^T, 256 thr / 4 waves.
// BK=64, LDS XOR-swizzled (chunk ^= row&7) for conflict-free ds_read_b128.
// MODE 1: A row = embed_bf[seq[m]]; C = relu(acc+bias) -> bf16
// MODE 2: A = t1 bf16;  C = acc + bias + embed_f32[seq[m]][n] -> f32
// MODE 3: A = h bf16;   C = acc + bias -> f32
// ---------------------------------------------------------------------------
template <int MODE, int K, int N>
__global__ __launch_bounds__(256) void gemm_mfma(
    const ushort_t* __restrict__ A, const ushort_t* __restrict__ BT,
    const float* __restrict__ bias, void* __restrict__ Cp,
    const int* __restrict__ seq, const float* __restrict__ embed)
{
    __shared__ __align__(16) ushort_t Asm[128 * 64];
    __shared__ __align__(16) ushort_t Bsm[128 * 64];

    const int tid = threadIdx.x;
    const int m0 = blockIdx.x * 128;
    const int n0 = blockIdx.y * 128;
    const int w = tid >> 6;
    const int l = tid & 63;
    const int wr = w >> 1;   // wave tile row (0..1)
    const int wc = w & 1;    // wave tile col (0..1)

    // staging row base pointers (rows fixed across K-loop)
    const ushort_t* arow[4];
    const ushort_t* brow[4];
#pragma unroll
    for (int i = 0; i < 4; ++i) {
        const int flat = i * 256 + tid;       // 0..1023
        const int r = flat >> 3;              // 0..127
        const int gr = (MODE == 1) ? seq[m0 + r] : (m0 + r);
        arow[i] = A + (size_t)gr * K;
        brow[i] = BT + (size_t)(n0 + r) * K;
    }

    f32x4 acc[4][4];
#pragma unroll
    for (int mi = 0; mi < 4; ++mi)
#pragma unroll
        for (int nj = 0; nj < 4; ++nj)
            acc[mi][nj] = (f32x4){0.f, 0.f, 0.f, 0.f};

    for (int kt = 0; kt < K / 64; ++kt) {
#pragma unroll
        for (int i = 0; i < 4; ++i) {
            const int flat = i * 256 + tid;
            const int r = flat >> 3;          // tile row
            const int c = flat & 7;           // 16B chunk within 128B row
            const int cs = c ^ (r & 7);       // swizzled chunk
            uint4 av = *(const uint4*)(arow[i] + kt * 64 + c * 8);
            *(uint4*)&Asm[r * 64 + cs * 8] = av;
            uint4 bv = *(const uint4*)(brow[i] + kt * 64 + c * 8);
            *(uint4*)&Bsm[r * 64 + cs * 8] = bv;
        }
        __syncthreads();
#pragma unroll
        for (int kh = 0; kh < 2; ++kh) {
            bf16x8 af[4], bfr[4];
#pragma unroll
            for (int mi = 0; mi < 4; ++mi) {
                const int r = wr * 64 + mi * 16 + (l & 15);
                const int c = (kh * 4 + (l >> 4)) ^ (r & 7);
                af[mi] = *(const bf16x8*)&Asm[r * 64 + c * 8];
            }
#pragma unroll
            for (int nj = 0; nj < 4; ++nj) {
                const int r = wc * 64 + nj * 16 + (l & 15);
                const int c = (kh * 4 + (l >> 4)) ^ (r & 7);
                bfr[nj] = *(const bf16x8*)&Bsm[r * 64 + c * 8];
            }
#pragma unroll
            for (int mi = 0; mi < 4; ++mi)
#pragma unroll
                for (int nj = 0; nj < 4; ++nj)
                    acc[mi][nj] = __builtin_amdgcn_mfma_f32_16x16x32_bf16(
                        af[mi], bfr[nj], acc[mi][nj], 0, 0, 0);
        }
        __syncthreads();
    }

    // epilogue: C/D layout col = lane&15, row = (lane>>4)*4 + reg
    const int cl = l & 15;
    const int rg = l >> 4;
    float bv[4];
#pragma unroll
    for (int nj = 0; nj < 4; ++nj)
        bv[nj] = bias[n0 + wc * 64 + nj * 16 + cl];

#pragma unroll
    for (int mi = 0; mi < 4; ++mi) {
#pragma unroll
        for (int i = 0; i < 4; ++i) {
            const int row = m0 + wr * 64 + mi * 16 + rg * 4 + i;  // chunk-local
            const float* erow = (MODE == 2)
                ? (embed + (size_t)seq[row] * H_SZ) : nullptr;
#pragma unroll
            for (int nj = 0; nj < 4; ++nj) {
                const int gn = n0 + wc * 64 + nj * 16 + cl;
                float v = acc[mi][nj][i] + bv[nj];
                if (MODE == 1) {
                    v = fmaxf(v, 0.f);
                    ((ushort_t*)Cp)[(size_t)row * N + gn] = f2bf(v);
                } else if (MODE == 2) {
                    ((float*)Cp)[(size_t)row * N + gn] = v + erow[gn];
                } else {
                    ((float*)Cp)[(size_t)row * N + gn] = v;
                }
            }
        }
    }
}

// ---------------------------------------------------------------------------
// LayerNorm over H=256: one wave per token, 4 tokens per block (chunk-local).
// ---------------------------------------------------------------------------
__global__ __launch_bounds__(256) void ln_k(
    const float* __restrict__ x, const float* __restrict__ g,
    const float* __restrict__ bt, ushort_t* __restrict__ h)
{
    const int token = blockIdx.x * 4 + (threadIdx.x >> 6);
    const int lane = threadIdx.x & 63;
    const float* xr = x + (size_t)token * H_SZ + lane * 4;
    const float4 v = *(const float4*)xr;
    float s = v.x + v.y + v.z + v.w;
    float sq = v.x * v.x + v.y * v.y + v.z * v.z + v.w * v.w;
#pragma unroll
    for (int m = 1; m < 64; m <<= 1) {
        s += __shfl_xor(s, m);
        sq += __shfl_xor(sq, m);
    }
    const float mu = s * (1.f / H_SZ);
    const float var = sq * (1.f / H_SZ) - mu * mu;
    const float rs = rsqrtf(var + 1e-5f);
    const int idx = lane * 4;
    const float4 gg = *(const float4*)(g + idx);
    const float4 bb = *(const float4*)(bt + idx);
    ushort_t o0 = f2bf((v.x - mu) * rs * gg.x + bb.x);
    ushort_t o1 = f2bf((v.y - mu) * rs * gg.y + bb.y);
    ushort_t o2 = f2bf((v.z - mu) * rs * gg.z + bb.z);
    ushort_t o3 = f2bf((v.w - mu) * rs * gg.w + bb.w);
    uint2 pk;
    pk.x = (uint32_t)o0 | ((uint32_t)o1 << 16);
    pk.y = (uint32_t)o2 | ((uint32_t)o3 << 16);
    *(uint2*)(h + (size_t)token * H_SZ + idx) = pk;
}

// ---------------------------------------------------------------------------
// Chunked backward scan, blocked-Gram formulation (exact algebra):
//   d_t = k_t . v_t ;  v_{t-1} = v_t - alpha_t d_t k_t ;  c += beta_t d_t k_t
// Blocked T=128: within chunk (u = t1 - t ascending):
//   d_u = a_u - sum_{j<u} alpha_j G[u][j] d_j,  a = K v_in,  G = K K^T
// then v -= K^T (alpha*d), c += K^T (beta*d).
// One block (4 waves) per (b,half) pair. K kept in LDS as bf16 hi+lo
// (hi+lo ~ f32-exact); Gram via MFMA (hi*hi + hi*lo + lo*hi).
// Also folds invn (alpha = beta/(|k|^2+1e-6)) into the stage pass.
// ---------------------------------------------------------------------------
__global__ __launch_bounds__(256) void scan_chunk_k(
    const float* __restrict__ proj, float* __restrict__ cbuf)
{
    __shared__ __align__(16) ushort_t Khi[128 * 128];   // 32 KB (swizzled)
    __shared__ __align__(16) ushort_t Klo[128 * 128];   // 32 KB (swizzled)
    __shared__ __align__(16) float G[128 * 128];        // 64 KB
    __shared__ float vv[128], cc[128], aa[128];
    __shared__ float al[128], be[128], ad[128], bd[128];
    __shared__ float pv[2][128], pc[2][128];

    const int pair = blockIdx.x;      // 0..127
    const int b = pair >> 1;
    const int half = pair & 1;
    const int tid = threadIdx.x;
    const int w = tid >> 6;
    const int l = tid & 63;

    const float* kbase = proj + (size_t)b * L_SZ * H_SZ + half * HALF_SZ;
    const float invL = 1.0f / (float)L_SZ;

    // init: v = q (token L-1), c = 0
    if (tid < 128) {
        vv[tid] = kbase[(size_t)(L_SZ - 1) * H_SZ + tid];
        cc[tid] = 0.f;
    }
    __syncthreads();

    for (int chk = 15; chk >= 0; --chk) {
        const int t1 = chk * 128 + 127;

        // ---- STAGE: rows u=0..127 = tokens t1-u; hi/lo bf16 + |k|^2 ----
        {
            const int u = tid >> 1, h = tid & 1;
            const int tok = t1 - u;
            const float* src = kbase + (size_t)tok * H_SZ + h * 64;
            float sq = 0.f;
#pragma unroll
            for (int g = 0; g < 8; ++g) {
                const float4 v0 = *(const float4*)(src + g * 8);
                const float4 v1 = *(const float4*)(src + g * 8 + 4);
                const float e[8] = {v0.x, v0.y, v0.z, v0.w,
                                    v1.x, v1.y, v1.z, v1.w};
                ushort_t hi8[8], lo8[8];
#pragma unroll
                for (int q = 0; q < 8; ++q) {
                    sq = fmaf(e[q], e[q], sq);
                    hi8[q] = f2bf(e[q]);
                    const float hf = __uint_as_float(((uint32_t)hi8[q]) << 16);
                    lo8[q] = f2bf(e[q] - hf);
                }
                const int cs = (h * 8 + g) ^ (u & 7);   // swizzled 8-elem chunk
                uint4 ph, pl;
                ph.x = (uint32_t)hi8[0] | ((uint32_t)hi8[1] << 16);
                ph.y = (uint32_t)hi8[2] | ((uint32_t)hi8[3] << 16);
                ph.z = (uint32_t)hi8[4] | ((uint32_t)hi8[5] << 16);
                ph.w = (uint32_t)hi8[6] | ((uint32_t)hi8[7] << 16);
                pl.x = (uint32_t)lo8[0] | ((uint32_t)lo8[1] << 16);
                pl.y = (uint32_t)lo8[2] | ((uint32_t)lo8[3] << 16);
                pl.z = (uint32_t)lo8[4] | ((uint32_t)lo8[5] << 16);
                pl.w = (uint32_t)lo8[6] | ((uint32_t)lo8[7] << 16);
                *(uint4*)&Khi[u * 128 + cs * 8] = ph;
                *(uint4*)&Klo[u * 128 + cs * 8] = pl;
            }
            sq += __shfl_xor(sq, 1);
            if (h == 0) {
                float bet, alp;
                if (tok == L_SZ - 1) { bet = 0.f; alp = 0.f; }  // q token inert
                else {
                    bet = half ? (float)(tok + 1) * invL : 1.0f;
                    alp = bet / (sq + 1e-6f);
                }
                al[u] = alp; be[u] = bet;
            }
        }
        __syncthreads();

        // ---- GRAM: G = K K^T via MFMA (hi*hi + hi*lo + lo*hi) ----
        {
#pragma unroll
            for (int tr = 0; tr < 2; ++tr) {
                const int ti = 2 * w + tr;
                const int ra = ti * 16 + (l & 15);
                bf16x8 ahi[4], alo[4];
#pragma unroll
                for (int ks = 0; ks < 4; ++ks) {
                    const int c = (ks * 4 + (l >> 4)) ^ (ra & 7);
                    ahi[ks] = *(const bf16x8*)&Khi[ra * 128 + c * 8];
                    alo[ks] = *(const bf16x8*)&Klo[ra * 128 + c * 8];
                }
#pragma unroll
                for (int tj = 0; tj < 8; ++tj) {
                    const int rb = tj * 16 + (l & 15);
                    f32x4 acc = (f32x4){0.f, 0.f, 0.f, 0.f};
#pragma unroll
                    for (int ks = 0; ks < 4; ++ks) {
                        const int c = (ks * 4 + (l >> 4)) ^ (rb & 7);
                        const bf16x8 bhi = *(const bf16x8*)&Khi[rb * 128 + c * 8];
                        const bf16x8 blo = *(const bf16x8*)&Klo[rb * 128 + c * 8];
                        acc = __builtin_amdgcn_mfma_f32_16x16x32_bf16(
                            ahi[ks], bhi, acc, 0, 0, 0);
                        acc = __builtin_amdgcn_mfma_f32_16x16x32_bf16(
                            ahi[ks], blo, acc, 0, 0, 0);
                        acc = __builtin_amdgcn_mfma_f32_16x16x32_bf16(
                            alo[ks], bhi, acc, 0, 0, 0);
                    }
                    const int col = tj * 16 + (l & 15);
                    const int rbase = ti * 16 + (l >> 4) * 4;
#pragma unroll
                    for (int i = 0; i < 4; ++i)
                        G[(rbase + i) * 128 + col] = acc[i];
                }
            }
        }

        // ---- GEMV: a_u = k_u . v  (f32, hi+lo reconstruct) ----
        {
            const int u = tid >> 1, h = tid & 1;
            float p = 0.f;
#pragma unroll
            for (int g = 0; g < 8; ++g) {
                const int cs = (h * 8 + g) ^ (u & 7);
                const uint4 ph = *(const uint4*)&Khi[u * 128 + cs * 8];
                const uint4 pl = *(const uint4*)&Klo[u * 128 + cs * 8];
                const float* vp = &vv[(h * 8 + g) * 8];
                const float4 w0 = *(const float4*)vp;
                const float4 w1 = *(const float4*)(vp + 4);
                const uint32_t Hh[4] = {ph.x, ph.y, ph.z, ph.w};
                const uint32_t Ll[4] = {pl.x, pl.y, pl.z, pl.w};
                const float wv[8] = {w0.x, w0.y, w0.z, w0.w,
                                     w1.x, w1.y, w1.z, w1.w};
#pragma unroll
                for (int q = 0; q < 4; ++q) {
                    const float k0 = __uint_as_float(Hh[q] << 16)
                                   + __uint_as_float(Ll[q] << 16);
                    const float k1 = __uint_as_float(Hh[q] & 0xffff0000u)
                                   + __uint_as_float(Ll[q] & 0xffff0000u);
                    p = fmaf(k0, wv[2 * q], p);
                    p = fmaf(k1, wv[2 * q + 1], p);
                }
            }
            p += __shfl_xor(p, 1);
            if (h == 0) aa[u] = p;
        }
        __syncthreads();

        // ---- SOLVE: serial d-chain (redundant per wave, lane owns 2 rows) ----
        {
            float acc0 = aa[l];
            float acc1 = aa[l + 64];
#pragma unroll 8
            for (int j = 0; j < 128; ++j) {
                const float cur = (j < 64) ? acc0 : acc1;
                const float db = __shfl(cur, j & 63);
                const float adj = al[j] * db;
                const float g0 = G[j * 128 + l];
                const float g1 = G[j * 128 + l + 64];
                acc0 -= ((l > j) ? adj : 0.f) * g0;
                acc1 -= ((l + 64 > j) ? adj : 0.f) * g1;
                if (w == 0 && l == (j & 63)) {
                    ad[j] = adj;
                    bd[j] = be[j] * db;
                }
            }
        }
        __syncthreads();

        // ---- UPDATE-A: partial v/c rank-128 update ----
        {
            const int g = tid >> 7;          // 0/1 -> j-range halves
            const int e = tid & 127;
            const int ch0 = e >> 3, o = e & 7;
            float pvv = 0.f, pcc = 0.f;
#pragma unroll 8
            for (int j = g * 64; j < g * 64 + 64; ++j) {
                const int idx = j * 128 + ((ch0 ^ (j & 7)) << 3) + o;
                const float k = __uint_as_float(((uint32_t)Khi[idx]) << 16)
                              + __uint_as_float(((uint32_t)Klo[idx]) << 16);
                pvv = fmaf(ad[j], k, pvv);
                pcc = fmaf(bd[j], k, pcc);
            }
            pv[g][e] = pvv; pc[g][e] = pcc;
        }
        __syncthreads();

        // ---- UPDATE-B: fold partials into v, c ----
        if (tid < 128) {
            vv[tid] -= pv[0][tid] + pv[1][tid];
            cc[tid] += pc[0][tid] + pc[1][tid];
        }
        __syncthreads();
    }

    if (tid < 128)
        cbuf[b * H_SZ + half * HALF_SZ + tid] = cc[tid];
}

// ---------------------------------------------------------------------------
// out[b, v] = sum_h c[b,h] * out_w[h,v] + out_b[v]   (f32 store)
// ---------------------------------------------------------------------------
__global__ __launch_bounds__(256) void out_k(
    const float* __restrict__ c, const float* __restrict__ w,
    const float* __restrict__ ob, float* __restrict__ out)
{
    const int b = blockIdx.x >> 2;
    const int v = ((blockIdx.x & 3) << 8) + threadIdx.x;
    const float* cb = c + b * H_SZ;
    float acc = ob[v];
#pragma unroll 4
    for (int hh = 0; hh < H_SZ; ++hh)
        acc = fmaf(cb[hh], w[(size_t)hh * V_SZ + v], acc);
    out[(size_t)b * V_SZ + v] = acc;
}

// ---------------------------------------------------------------------------
extern "C" void kernel_launch(void* const* d_in, const int* in_sizes, int n_in,
                              void* d_out, int out_size, void* d_ws, size_t ws_size,
                              hipStream_t stream)
{
    const int*   seq   = (const int*)d_in[0];
    const float* embed = (const float*)d_in[1];
    const float* w1    = (const float*)d_in[2];
    const float* b1    = (const float*)d_in[3];
    const float* w2    = (const float*)d_in[4];
    const float* b2    = (const float*)d_in[5];
    const float* ln_g  = (const float*)d_in[6];
    const float* ln_b  = (const float*)d_in[7];
    const float* kp_w  = (const float*)d_in[8];
    const float* kp_b  = (const float*)d_in[9];
    const float* out_w = (const float*)d_in[10];
    const float* out_b = (const float*)d_in[11];

    char* ws = (char*)d_ws;
    size_t off = 0;
    auto alloc = [&](size_t bytes) -> void* {
        void* p = ws + off;
        off += (bytes + 255) & ~(size_t)255;
        return p;
    };

    float*    proj = (float*)alloc((size_t)NTOK * H_SZ * sizeof(float));     // 128 MB
    ushort_t* t1_c = (ushort_t*)alloc((size_t)CH * 512 * sizeof(ushort_t));  // 16 MB
    float*    x_c  = (float*)alloc((size_t)CH * H_SZ * sizeof(float));       // 16 MB
    ushort_t* h_c  = (ushort_t*)alloc((size_t)CH * H_SZ * sizeof(ushort_t)); // 8 MB
    float*    cbuf = (float*)alloc((size_t)B_SZ * H_SZ * sizeof(float));
    // bf16 weight copies
    ushort_t* embed_bf = (ushort_t*)alloc((size_t)V_SZ * H_SZ * 2);          // 512 KB
    ushort_t* w1T = (ushort_t*)alloc((size_t)512 * 256 * 2);                 // 256 KB
    ushort_t* w2T = (ushort_t*)alloc((size_t)256 * 512 * 2);                 // 256 KB
    ushort_t* kpT = (ushort_t*)alloc((size_t)256 * 256 * 2);                 // 128 KB
    float*    outp = (float*)d_out;

    const dim3 blk(256);

    // weight preconversion (bf16 / transposed-bf16)
    cvt_bf16_k<<<dim3((V_SZ * H_SZ) / 1024), blk, 0, stream>>>(
        embed, embed_bf, V_SZ * H_SZ);
    transpose_cvt_k<<<dim3((256 * 512) / 256), blk, 0, stream>>>(w1, w1T, 256, 512);
    transpose_cvt_k<<<dim3((512 * 256) / 256), blk, 0, stream>>>(w2, w2T, 512, 256);
    transpose_cvt_k<<<dim3((256 * 256) / 256), blk, 0, stream>>>(kp_w, kpT, 256, 256);

    for (int c = 0; c < NTOK / CH; ++c) {
        const int base = c * CH;
        const int* seq_c = seq + base;
        // GEMM1: t1 = relu(embed[seq] @ w1 + b1)     M=CH K=256 N=512
        gemm_mfma<1, 256, 512><<<dim3(CH / 128, 4), blk, 0, stream>>>(
            embed_bf, w1T, b1, t1_c, seq_c, nullptr);
        // GEMM2: x = t1 @ w2 + b2 + embed[seq]       M=CH K=512 N=256
        gemm_mfma<2, 512, 256><<<dim3(CH / 128, 2), blk, 0, stream>>>(
            t1_c, w2T, b2, x_c, seq_c, embed);
        // LN: h = LN(x) * g + b  (bf16)
        ln_k<<<dim3(CH / 4), blk, 0, stream>>>(x_c, ln_g, ln_b, h_c);
        // GEMM3: proj = h @ kp_w + kp_b              M=CH K=256 N=256
        gemm_mfma<3, 256, 256><<<dim3(CH / 128, 2), blk, 0, stream>>>(
            h_c, kpT, kp_b, proj + (size_t)base * H_SZ, seq_c, nullptr);
    }

    // chunked blocked-Gram backward scan: c = M_final q (invn folded in)
    scan_chunk_k<<<dim3(128), blk, 0, stream>>>(proj, cbuf);
    out_k<<<dim3(B_SZ * 4), blk, 0, stream>>>(cbuf, out_w, out_b, outp);
}